// Round 14
// baseline (7711.266 us; speedup 1.0000x reference)
//
#include <hip/hip_runtime.h>

typedef __attribute__((ext_vector_type(8))) short short8;
typedef __attribute__((ext_vector_type(4))) float f32x4;
typedef unsigned short u16;
typedef unsigned int u32;

// ---------------- workspace layout (bytes) ----------------
// xb:  [512 t][64 b][512 i] bf16                        = 33,554,432
// h0h: [513 slot][4 g][16 b][1024 u] bf16 (slot t+1)    = 67,239,936
// h1h: same                                             = 67,239,936
// flags: [2 layer][4 g][256 cu] monotonic, 32B stride   = 65,536
#define XB_OFF 0ul
#define H0_OFF 33554432ul
#define H1_OFF 100794368ul
#define FL_OFF 168034304ul
#define FLAGS_LEN 65536ul

// ---------------- LDS layout ----------------
// L0 W block: 16 cols x 3108 B (1536 bf16 + 36B pad, stride ≡ 9 mod 32 dwords)
// L1 W block: 16 cols x 4132 B (2048 bf16 + 36B pad)
#define S0B 3108
#define S1B 4132
#define L1OFF 49728              // 16*S0B
#define LDS_TOTAL 115840         // L1OFF + 16*S1B

__device__ __forceinline__ u16 f2bf(float f) {
  u32 u = __float_as_uint(f);
  return (u16)((u + 0x7fffu + ((u >> 16) & 1u)) >> 16);   // RNE
}
__device__ __forceinline__ float bf2f(u16 s) { return __uint_as_float(((u32)s) << 16); }

// x[b][t][i] fp32 -> xb[t][b][i] bf16
__global__ __launch_bounds__(256) void prep_x(const float* __restrict__ x,
                                              u16* __restrict__ xb) {
  u32 stride = gridDim.x * blockDim.x;
  for (u32 e = blockIdx.x * blockDim.x + threadIdx.x; e < 16777216u; e += stride) {
    u32 i = e & 511u, b = (e >> 9) & 63u, t = e >> 15;
    xb[e] = f2bf(x[((size_t)b << 18) + ((size_t)t << 9) + i]);
  }
}

// Persistent kernel: 256 blocks (1/CU) x 256 threads (4 autonomous wave-chains).
// EVERY CU owns units [4cu, 4cu+4) of BOTH layers. Per round t, each wave
// (batch-group g of 16): L0(t) sweep -> publish h0(t) -> L1(t-1) sweep (REUSES
// the h0(t-1) fragments) -> publish h1(t-1) -> prefetch x -> joint poll ->
// load h0(t). The h0 publish->detect hop hides under the L1 sweep; h1's
// dependency is 2 rounds stale. W cols packed n = u*4+gate so each lane holds
// i,f,g,o of one unit for one batch: lane-local cell, 2B/lane publish.
__global__ __launch_bounds__(256, 1) void lstm_persist(
    const u16* __restrict__ xb,
    const float* __restrict__ wih0, const float* __restrict__ whh0,
    const float* __restrict__ bih0, const float* __restrict__ bhh0,
    const float* __restrict__ wih1, const float* __restrict__ whh1,
    const float* __restrict__ bih1, const float* __restrict__ bhh1,
    u16* __restrict__ h0h, u16* __restrict__ h1h,
    u32* __restrict__ flags,
    const float* __restrict__ fc_w, const float* __restrict__ fc_b,
    float* __restrict__ out) {
  extern __shared__ char smem[];
  const int cu = blockIdx.x;          // owns units 4cu..4cu+3, both layers
  const int U0 = cu * 4;
  const int tid = threadIdx.x;

  // ---- startup: pack 16 W cols per layer; col n = unit(n>>2)*4 + gate(n&3) ----
  for (int n = 0; n < 16; ++n) {
    const int grow = (n & 3) * 1024 + U0 + (n >> 2);
    u16* c0 = (u16*)(smem + n * S0B);
    const float* rih = wih0 + (size_t)grow * 512;
    const float* rhh = whh0 + (size_t)grow * 1024;
    for (int k = tid; k < 1536; k += 256)
      c0[k] = f2bf(k < 512 ? rih[k] : rhh[k - 512]);
    u16* c1 = (u16*)(smem + L1OFF + n * S1B);
    const float* qih = wih1 + (size_t)grow * 1024;
    const float* qhh = whh1 + (size_t)grow * 1024;
    for (int k = tid; k < 2048; k += 256)
      c1[k] = f2bf(k < 1024 ? qih[k] : qhh[k - 1024]);
  }
  __syncthreads();   // last barrier before the main loop

  const int g = tid >> 6, lane = tid & 63, lr = lane & 15, lq = lane >> 4;
  const char* a0base = smem + (size_t)lr * S0B + lq * 16;          // + tile*64
  const char* a1base = smem + L1OFF + (size_t)lr * S1B + lq * 16;

  // per-lane biases: lane = unit U0+lq, gates r=0..3 (i,f,g,o)
  float b0v[4], b1v[4];
  #pragma unroll
  for (int r = 0; r < 4; ++r) {
    b0v[r] = bih0[r * 1024 + U0 + lq] + bhh0[r * 1024 + U0 + lq];
    b1v[r] = bih1[r * 1024 + U0 + lq] + bhh1[r * 1024 + U0 + lq];
  }
  float c0s = 0.f, c1s = 0.f;

  u32* fl0 = flags;                                  // [g][256 cu] * 8 u32
  u32* fl1 = flags + 4 * 256 * 8;
  const u32* f0g = fl0 + (size_t)g * 2048;
  const u32* f1g = fl1 + (size_t)g * 2048;
  u32* myf0 = fl0 + ((size_t)g * 256 + cu) * 8;
  u32* myf1 = fl1 + ((size_t)g * 256 + cu) * 8;

  const size_t pidx = (size_t)g * 16384 + (size_t)lr * 1024 + (U0 + lq); // store
  const size_t cidx = (size_t)g * 16384 + (size_t)lr * 1024 + 8 * lq;    // frag

  short8 X[16], H0[32], H1[32];
  { // X(0)
    const u16* xp = xb + (size_t)(g * 16 + lr) * 512 + 8 * lq;
    #pragma unroll
    for (int j = 0; j < 16; ++j) X[j] = *(const short8*)(xp + j * 32);
  }

  for (int t = 0; t <= 512; ++t) {
    if (t < 512) {
      // ---------------- L0(t): 16 x-tiles + 32 h0(t-1)-tiles ----------------
      f32x4 acc = {0.f, 0.f, 0.f, 0.f};
      #pragma unroll
      for (int j = 0; j < 16; ++j) {
        short8 a = *(const short8*)(a0base + j * 64);
        acc = __builtin_amdgcn_mfma_f32_16x16x32_bf16(a, X[j], acc, 0, 0, 0);
      }
      if (t > 0) {
        #pragma unroll
        for (int j = 0; j < 32; ++j) {
          short8 a = *(const short8*)(a0base + (16 + j) * 64);
          acc = __builtin_amdgcn_mfma_f32_16x16x32_bf16(a, H0[j], acc, 0, 0, 0);
        }
      }
      float gi = acc[0] + b0v[0], gf = acc[1] + b0v[1];
      float gg = acc[2] + b0v[2], go = acc[3] + b0v[3];
      float ii = 1.f / (1.f + __expf(-gi));
      float ff = 1.f / (1.f + __expf(-gf));
      float gt = 1.f - 2.f / (__expf(2.f * gg) + 1.f);
      float oo = 1.f / (1.f + __expf(-go));
      c0s = ff * c0s + ii * gt;
      u32 hv = (u32)f2bf(oo * (1.f - 2.f / (__expf(2.f * c0s) + 1.f)));
      u16* dst = h0h + (size_t)(t + 1) * 65536 + pidx;
      asm volatile("global_store_short %0, %1, off sc0 sc1" :: "v"(dst), "v"(hv) : "memory");
      asm volatile("s_waitcnt vmcnt(0)" ::: "memory");   // 2B store ack'd
      if (lane == 0)
        asm volatile("global_store_dword %0, %1, off sc0 sc1"
                     :: "v"(myf0), "v"((u32)(t + 1)) : "memory");
    }
    if (t > 0) {
      // ------------- L1(t-1): 32 h0(t-1)-tiles (reused) + 32 h1(t-2) -------
      { // H1 loads (slot t-1, flag f1>=t-1 verified last round); hide under sweep
        const u16* hp = h1h + (size_t)(t - 1) * 65536 + cidx;
        #pragma unroll
        for (int j = 0; j < 32; ++j) H1[j] = *(const short8*)(hp + j * 32);
      }
      f32x4 acc = {0.f, 0.f, 0.f, 0.f};
      #pragma unroll
      for (int j = 0; j < 32; ++j) {
        short8 a = *(const short8*)(a1base + j * 64);
        acc = __builtin_amdgcn_mfma_f32_16x16x32_bf16(a, H0[j], acc, 0, 0, 0);
      }
      #pragma unroll
      for (int j = 0; j < 32; ++j) {
        short8 a = *(const short8*)(a1base + (32 + j) * 64);
        acc = __builtin_amdgcn_mfma_f32_16x16x32_bf16(a, H1[j], acc, 0, 0, 0);
      }
      float gi = acc[0] + b1v[0], gf = acc[1] + b1v[1];
      float gg = acc[2] + b1v[2], go = acc[3] + b1v[3];
      float ii = 1.f / (1.f + __expf(-gi));
      float ff = 1.f / (1.f + __expf(-gf));
      float gt = 1.f - 2.f / (__expf(2.f * gg) + 1.f);
      float oo = 1.f / (1.f + __expf(-go));
      c1s = ff * c1s + ii * gt;
      u32 hv = (u32)f2bf(oo * (1.f - 2.f / (__expf(2.f * c1s) + 1.f)));
      u16* dst = h1h + (size_t)t * 65536 + pidx;          // h1(t-1) -> slot t
      asm volatile("global_store_short %0, %1, off sc0 sc1" :: "v"(dst), "v"(hv) : "memory");
      asm volatile("s_waitcnt vmcnt(0)" ::: "memory");
      if (lane == 0)
        asm volatile("global_store_dword %0, %1, off sc0 sc1"
                     :: "v"(myf1), "v"((u32)t) : "memory");
    }
    if (t < 512) {
      { // prefetch X(t+1) (plain cached)
        const int tx = (t + 1 < 512) ? t + 1 : 511;
        const u16* xp = xb + (size_t)tx * 32768 + (size_t)(g * 16 + lr) * 512 + 8 * lq;
        #pragma unroll
        for (int j = 0; j < 16; ++j) X[j] = *(const short8*)(xp + j * 32);
      }
      // joint poll: f0 >= t+1 (h0(t), fresh) AND f1 >= t (h1(t-1))
      const u32 T0 = (u32)(t + 1), T1 = (u32)t;
      const u32* p0 = f0g + (u32)lane * 8u;
      const u32* q0 = f1g + (u32)lane * 8u;
      for (;;) {
        u32 a0, a1, a2, a3, e0, e1, e2, e3;
        asm volatile(
            "global_load_dword %0, %8, off sc0 sc1\n\t"
            "global_load_dword %1, %9, off sc0 sc1\n\t"
            "global_load_dword %2, %10, off sc0 sc1\n\t"
            "global_load_dword %3, %11, off sc0 sc1\n\t"
            "global_load_dword %4, %12, off sc0 sc1\n\t"
            "global_load_dword %5, %13, off sc0 sc1\n\t"
            "global_load_dword %6, %14, off sc0 sc1\n\t"
            "global_load_dword %7, %15, off sc0 sc1\n\t"
            "s_waitcnt vmcnt(0)"
            : "=v"(a0), "=v"(a1), "=v"(a2), "=v"(a3),
              "=v"(e0), "=v"(e1), "=v"(e2), "=v"(e3)
            : "v"(p0), "v"(p0 + 512), "v"(p0 + 1024), "v"(p0 + 1536),
              "v"(q0), "v"(q0 + 512), "v"(q0 + 1024), "v"(q0 + 1536)
            : "memory");
        if (__all((int)((a0 >= T0) & (a1 >= T0) & (a2 >= T0) & (a3 >= T0) &
                        (e0 >= T1) & (e1 >= T1) & (e2 >= T1) & (e3 >= T1))))
          break;
        __builtin_amdgcn_s_sleep(1);
      }
      { // load H0 = h0(t) fragments (slot t+1), shared by L0(t+1) and L1(t)
        const u16* hp = h0h + (size_t)(t + 1) * 65536 + cidx;
        #pragma unroll
        for (int j = 0; j < 32; ++j) H0[j] = *(const short8*)(hp + j * 32);
      }
    }
  }

  // ---- FC + softmax epilogue: block 0, wave 0 (reads h1[511] = slot 512) ----
  if (cu == 0 && g == 0) {
    #pragma unroll
    for (int j = 0; j < 16; ++j) {     // all 1024 layer-1 flags >= 512
      const u32* p = (flags + 4 * 256 * 8) + (size_t)(j * 64 + lane) * 8;
      for (;;) {
        u32 v;
        asm volatile("global_load_dword %0, %1, off sc0 sc1\n\ts_waitcnt vmcnt(0)"
                     : "=v"(v) : "v"(p) : "memory");
        if (v >= 512u) break;
        __builtin_amdgcn_s_sleep(1);
      }
    }
    const int b = lane;                // one batch per lane
    const u16* hb = h1h + (size_t)512 * 65536 + (size_t)(b >> 4) * 16384
                    + (size_t)(b & 15) * 1024;
    float s0 = fc_b[0], s1 = fc_b[1];
    for (int c = 0; c < 128; ++c) {
      short8 hv8 = *(const short8*)(hb + c * 8);
      #pragma unroll
      for (int e = 0; e < 8; ++e) {
        float hv = bf2f((u16)hv8[e]);
        s0 += hv * fc_w[c * 8 + e];
        s1 += hv * fc_w[1024 + c * 8 + e];
      }
    }
    float mx = fmaxf(s0, s1);
    float e0 = __expf(s0 - mx), e1 = __expf(s1 - mx);
    float inv = 1.f / (e0 + e1);
    out[b * 2]     = e0 * inv;
    out[b * 2 + 1] = e1 * inv;
  }
}

extern "C" void kernel_launch(void* const* d_in, const int* in_sizes, int n_in,
                              void* d_out, int out_size, void* d_ws, size_t ws_size,
                              hipStream_t stream) {
  const float* x    = (const float*)d_in[0];
  const float* wih0 = (const float*)d_in[1];
  const float* whh0 = (const float*)d_in[2];
  const float* bih0 = (const float*)d_in[3];
  const float* bhh0 = (const float*)d_in[4];
  const float* wih1 = (const float*)d_in[5];
  const float* whh1 = (const float*)d_in[6];
  const float* bih1 = (const float*)d_in[7];
  const float* bhh1 = (const float*)d_in[8];
  const float* fcw  = (const float*)d_in[9];
  const float* fcb  = (const float*)d_in[10];
  float* out = (float*)d_out;
  char* ws = (char*)d_ws;

  u16* xb    = (u16*)(ws + XB_OFF);
  u16* h0h   = (u16*)(ws + H0_OFF);
  u16* h1h   = (u16*)(ws + H1_OFF);
  u32* flags = (u32*)(ws + FL_OFF);

  (void)hipFuncSetAttribute((const void*)lstm_persist,
      hipFuncAttributeMaxDynamicSharedMemorySize, LDS_TOTAL);

  hipMemsetAsync(ws + FL_OFF, 0, FLAGS_LEN, stream);   // zero flags
  hipMemsetAsync(ws + H0_OFF, 0, 131072, stream);      // h0 slot 0 = 0
  hipMemsetAsync(ws + H1_OFF, 0, 131072, stream);      // h1 slot 0 = 0 (h1(-1))
  prep_x<<<8192, 256, 0, stream>>>(x, xb);
  lstm_persist<<<256, 256, LDS_TOTAL, stream>>>(
      (const u16*)xb, wih0, whh0, bih0, bhh0, wih1, whh1, bih1, bhh1,
      h0h, h1h, flags, fcw, fcb, out);
}

// Round 15
// 4997.035 us; speedup vs baseline: 1.5432x; 1.5432x over previous
//
#include <hip/hip_runtime.h>

typedef __attribute__((ext_vector_type(8))) short short8;
typedef __attribute__((ext_vector_type(4))) float f32x4;
typedef __attribute__((ext_vector_type(2))) unsigned int u32x2;
typedef unsigned short u16;
typedef unsigned int u32;

// ---------------- workspace layout (bytes) ----------------
// xb:  [512 t][64 b][512 i] bf16                              = 33,554,432
// h0h: [513][4 g][128 chunk][16 b][8 u] bf16 (slot t+1=h[t])  = 67,239,936
// h1h: same                                                   = 67,239,936
// flags: [2 layer][4 group][128 chunk] monotonic, 32B stride  = 32,768
#define XB_OFF 0ul
#define H0_OFF 33554432ul
#define H1_OFF 100794368ul
#define FL_OFF 168034304ul
#define FLAGS_LEN 32768ul

#define LDS_TOTAL 131072   // weights only: 32 cols * K2 (K2=4096B for layer1)

__device__ __forceinline__ u16 f2bf(float f) {
  u32 u = __float_as_uint(f);
  return (u16)((u + 0x7fffu + ((u >> 16) & 1u)) >> 16);   // RNE
}
__device__ __forceinline__ float bf2f(u16 s) { return __uint_as_float(((u32)s) << 16); }

// x[b][t][i] fp32 -> xb[t][b][i] bf16
__global__ __launch_bounds__(256) void prep_x(const float* __restrict__ x,
                                              u16* __restrict__ xb) {
  u32 stride = gridDim.x * blockDim.x;
  for (u32 e = blockIdx.x * blockDim.x + threadIdx.x; e < 16777216u; e += stride) {
    u32 i = e & 511u, b = (e >> 9) & 63u, t = e >> 15;
    xb[e] = f2bf(x[((size_t)b << 18) + ((size_t)t << 9) + i]);
  }
}

// Persistent kernel, 256 blocks (1/CU), 256 threads (4 autonomous wave-chains).
// Blocks 0..127: layer0 (K=1536=[x|h0prev]); 128..255: layer1 (K=2048=[h0|h1prev]).
// R11 structure + merged drain+flag-sample publish (stores and next-step flag
// samples share one vmcnt(0); flag store timing unchanged) + dual k-parity accs.
__global__ __launch_bounds__(256, 1) void lstm_persist(
    const u16* __restrict__ xb,
    const float* __restrict__ wih0, const float* __restrict__ whh0,
    const float* __restrict__ bih0, const float* __restrict__ bhh0,
    const float* __restrict__ wih1, const float* __restrict__ whh1,
    const float* __restrict__ bih1, const float* __restrict__ bhh1,
    u16* __restrict__ h0h, u16* __restrict__ h1h,
    u32* __restrict__ flags,
    const float* __restrict__ fc_w, const float* __restrict__ fc_b,
    float* __restrict__ out) {
  extern __shared__ char smem[];
  const int cu = blockIdx.x;
  const int layer = cu >> 7;
  const int lcu = cu & 127;
  const int U0 = lcu * 8;
  const int K2 = layer ? 4096 : 3072;         // bytes per LDS weight column
  const int tid = threadIdx.x;

  // ---- startup: pack 32 weight cols (col-major k, byte ^ (n&7)<<4) ----
  for (int n = 0; n < 32; ++n) {
    const int grow = (n >> 3) * 1024 + U0 + (n & 7);
    char* colbase = smem + n * K2;
    const u32 swn = (u32)(n & 7) << 4;
    if (!layer) {
      const float* rih = wih0 + (size_t)grow * 512;
      const float* rhh = whh0 + (size_t)grow * 1024;
      for (int k = tid; k < 1536; k += 256) {
        float v = (k < 512) ? rih[k] : rhh[k - 512];
        *(u16*)(colbase + (((u32)k * 2u) ^ swn)) = f2bf(v);
      }
    } else {
      const float* rih = wih1 + (size_t)grow * 1024;
      const float* rhh = whh1 + (size_t)grow * 1024;
      for (int k = tid; k < 2048; k += 256) {
        float v = (k < 1024) ? rih[k] : rhh[k - 1024];
        *(u16*)(colbase + (((u32)k * 2u) ^ swn)) = f2bf(v);
      }
    }
  }
  __syncthreads();   // last barrier before the main loop

  const int g = tid >> 6;            // wave = batch group (16 batches)
  const int lane = tid & 63;
  const int lr = lane & 15;          // batch row / W-col row within tile
  const int lq = lane >> 4;
  const u32 swz = (u32)(lr & 7) << 4;
  const char* wrow0 = smem + (size_t)lr * K2;         // cols 0-15 (i|f units)
  const char* wrow1 = smem + (size_t)(16 + lr) * K2;  // cols 16-31 (g|o units)

  // per-lane bias regs: unit u = 4*(lq&1) + r (valid for lq<2 output lanes)
  float bi[4], bf_[4], bg[4], bo[4];
  {
    const float* s1 = layer ? bih1 : bih0;
    const float* s2 = layer ? bhh1 : bhh0;
    const int ug = U0 + 4 * (lq & 1);
    #pragma unroll
    for (int r = 0; r < 4; ++r) {
      bi[r]  = s1[ug + r]        + s2[ug + r];
      bf_[r] = s1[1024 + ug + r] + s2[1024 + ug + r];
      bg[r]  = s1[2048 + ug + r] + s2[2048 + ug + r];
      bo[r]  = s1[3072 + ug + r] + s2[3072 + ug + r];
    }
  }
  float cs[4] = {0.f, 0.f, 0.f, 0.f};

  const u32* f0g = flags + (size_t)(0 * 4 + g) * 1024;   // 128 flags * 8 u32 stride
  const u32* f1g = flags + (size_t)(4 + g) * 1024;
  u32* myflag = flags + ((size_t)(layer * 4 + g) * 128 + (size_t)lcu) * 8;

  // own-chunk masks (own-layer flag arrays only; own data self-consistent)
  const u32 sm1 = (lcu < 64 && lane == lcu) ? 0xFFFFFFFFu : 0u;
  const u32 sm2 = (lcu >= 64 && lane == lcu - 64) ? 0xFFFFFFFFu : 0u;

  // flag-sample flights (vmcnt(0) inside also drains any prior stores/loads)
  auto pv2 = [&](const u32* base, u32& a, u32& b) {
    const u32* p1 = base + (u32)lane * 8u;
    const u32* p2 = base + (u32)(lane + 64) * 8u;
    asm volatile("global_load_dword %0, %2, off sc0 sc1\n\t"
                 "global_load_dword %1, %3, off sc0 sc1\n\t"
                 "s_waitcnt vmcnt(0)"
                 : "=v"(a), "=v"(b) : "v"(p1), "v"(p2) : "memory");
  };
  auto pv4 = [&](u32& a, u32& b, u32& c, u32& d) {   // f1 pair + f0 pair
    const u32* p1 = f1g + (u32)lane * 8u;
    const u32* p2 = f1g + (u32)(lane + 64) * 8u;
    const u32* p3 = f0g + (u32)lane * 8u;
    const u32* p4 = f0g + (u32)(lane + 64) * 8u;
    asm volatile("global_load_dword %0, %4, off sc0 sc1\n\t"
                 "global_load_dword %1, %5, off sc0 sc1\n\t"
                 "global_load_dword %2, %6, off sc0 sc1\n\t"
                 "global_load_dword %3, %7, off sc0 sc1\n\t"
                 "s_waitcnt vmcnt(0)"
                 : "=v"(a), "=v"(b), "=v"(c), "=v"(d)
                 : "v"(p1), "v"(p2), "v"(p3), "v"(p4) : "memory");
  };

  f32x4 z4 = {0.f, 0.f, 0.f, 0.f};
  f32x4 acc0[2], acc1[2];    // [k-parity]; tile0: cols 0-15, tile1: cols 16-31

  auto mfma2 = [&](short8 hb8, int k0, int p) {
    const u32 kb = ((u32)(k0 + lq * 8) * 2u) ^ swz;
    short8 a0 = *(const short8*)(wrow0 + kb);
    short8 a1 = *(const short8*)(wrow1 + kb);
    acc0[p] = __builtin_amdgcn_mfma_f32_16x16x32_bf16(a0, hb8, acc0[p], 0, 0, 0);
    acc1[p] = __builtin_amdgcn_mfma_f32_16x16x32_bf16(a1, hb8, acc1[p], 0, 0, 0);
  };

  // cell update (shfl-pair) + 8B data store (lq<2). Caller: sample+drain+flag.
  auto cell_store = [&](int t, u16* hist) {
    f32x4 s0, s1v;
    #pragma unroll
    for (int r = 0; r < 4; ++r) {
      s0[r] = acc0[0][r] + acc0[1][r];
      s1v[r] = acc1[0][r] + acc1[1][r];
    }
    float pf[4], po[4];
    #pragma unroll
    for (int r = 0; r < 4; ++r) {
      pf[r] = __shfl_xor(s0[r], 32);   // partner's f (for lq<2)
      po[r] = __shfl_xor(s1v[r], 32);  // partner's o (for lq<2)
    }
    if (lq < 2) {
      u16 hb16[4];
      #pragma unroll
      for (int r = 0; r < 4; ++r) {
        float gi = s0[r]  + bi[r];
        float gf = pf[r]  + bf_[r];
        float gg = s1v[r] + bg[r];
        float go = po[r]  + bo[r];
        float ii = 1.0f / (1.0f + __expf(-gi));
        float ff = 1.0f / (1.0f + __expf(-gf));
        float gt = 1.0f - 2.0f / (__expf(2.0f * gg) + 1.0f);
        float oo = 1.0f / (1.0f + __expf(-go));
        cs[r] = ff * cs[r] + ii * gt;
        hb16[r] = f2bf(oo * (1.0f - 2.0f / (__expf(2.0f * cs[r]) + 1.0f)));
      }
      u32x2 pk;
      pk.x = (u32)hb16[0] | ((u32)hb16[1] << 16);
      pk.y = (u32)hb16[2] | ((u32)hb16[3] << 16);
      u16* dst = hist + (size_t)(t + 1) * 65536 + (size_t)g * 16384
                 + (size_t)lcu * 128 + (size_t)lr * 8 + 4 * lq;
      asm volatile("global_store_dwordx2 %0, %1, off sc0 sc1" :: "v"(dst), "v"(pk));
    }
  };
  auto flag_pub = [&](int t) {
    if (lane == 0)
      asm volatile("global_store_dword %0, %1, off sc0 sc1"
                   :: "v"(myflag), "v"((u32)(t + 1)));
  };

  if (!layer) {
    // ================= layer 0: tiles 0..15 = x, 16..47 = h0prev =============
    u32 v1 = 0, v2 = 0;               // pre-sampled f0 values
    for (int t = 0; t < 512; ++t) {
      acc0[0] = z4; acc0[1] = z4; acc1[0] = z4; acc1[1] = z4;
      const u16* xp = xb + (size_t)t * 32768 + (size_t)(g * 16 + lr) * 512 + lq * 8;
      short8 X[16];
      #pragma unroll
      for (int j = 0; j < 16; ++j) X[j] = *(const short8*)(xp + j * 32);
      if (t > 0) {
        const u32 tt = (u32)t;
        while (!__all((int)(((v1 | sm1) >= tt) & ((v2 | sm2) >= tt)))) {
          __builtin_amdgcn_s_sleep(1);
          pv2(f0g, v1, v2);
        }
        const u16* hp = h0h + (size_t)t * 65536 + (size_t)g * 16384 + (size_t)lr * 8;
        short8 H[32];
        #pragma unroll
        for (int j = 0; j < 32; ++j)
          H[j] = *(const short8*)(hp + (size_t)(j * 4 + lq) * 128);
        #pragma unroll
        for (int j = 0; j < 16; ++j) mfma2(X[j], j * 32, j & 1);
        #pragma unroll
        for (int j = 0; j < 32; ++j) mfma2(H[j], 512 + j * 32, j & 1);
      } else {
        #pragma unroll
        for (int j = 0; j < 16; ++j) mfma2(X[j], j * 32, j & 1);
      }
      cell_store(t, h0h);
      pv2(f0g, v1, v2);     // merged: drains data stores + samples next-step flags
      flag_pub(t);
    }
  } else {
    // ============== layer 1: tiles 0..31 = h0cur, 32..63 = h1prev ===========
    u32 w1 = 0, w2 = 0, v1 = 0, v2 = 0;   // pre-sampled f1 / f0 values
    for (int t = 0; t < 512; ++t) {
      acc0[0] = z4; acc0[1] = z4; acc1[0] = z4; acc1[1] = z4;
      short8 A[32], Bv[32];
      if (t > 0) {
        const u32 ta = (u32)t;
        while (!__all((int)(((w1 | sm1) >= ta) & ((w2 | sm2) >= ta)))) {
          __builtin_amdgcn_s_sleep(1);
          pv2(f1g, w1, w2);
        }
        const u16* h1p = h1h + (size_t)t * 65536 + (size_t)g * 16384 + (size_t)lr * 8;
        #pragma unroll
        for (int j = 0; j < 32; ++j)      // H1 loads issue; fly during f0 wait
          A[j] = *(const short8*)(h1p + (size_t)(j * 4 + lq) * 128);
      }
      const u32 tb = (u32)(t + 1);
      while (!__all((int)((v1 >= tb) & (v2 >= tb)))) {   // no self in f0
        __builtin_amdgcn_s_sleep(1);
        pv2(f0g, v1, v2);               // vmcnt(0) also completes H1 flight
      }
      const u16* h0p = h0h + (size_t)(t + 1) * 65536 + (size_t)g * 16384 + (size_t)lr * 8;
      #pragma unroll
      for (int j = 0; j < 32; ++j)
        Bv[j] = *(const short8*)(h0p + (size_t)(j * 4 + lq) * 128);
      if (t > 0) {
        #pragma unroll
        for (int j = 0; j < 32; ++j) mfma2(A[j], 1024 + j * 32, j & 1);  // ∥ H0 flight
      }
      #pragma unroll
      for (int j = 0; j < 32; ++j) mfma2(Bv[j], j * 32, j & 1);
      cell_store(t, h1h);
      pv4(w1, w2, v1, v2);  // merged: drains data stores + samples f1 and f0
      flag_pub(t);
    }
  }

  // ---- FC + softmax epilogue: block 0, wave 0 (reads h1[511] = slot 512) ----
  if (cu == 0 && g == 0) {
    #pragma unroll
    for (int j = 0; j < 8; ++j) {   // all 512 layer-1 flags >= 512
      const u32* p = flags + (size_t)(512 + j * 64 + lane) * 8;
      for (;;) {
        u32 v;
        asm volatile("global_load_dword %0, %1, off sc0 sc1\n\ts_waitcnt vmcnt(0)"
                     : "=v"(v) : "v"(p) : "memory");
        if (v >= 512u) break;
        __builtin_amdgcn_s_sleep(1);
      }
    }
    const int b = lane;                       // one batch per lane
    const u16* hb = h1h + (size_t)512 * 65536 + (size_t)(b >> 4) * 16384
                    + (size_t)(b & 15) * 8;
    float s0 = fc_b[0], s1 = fc_b[1];
    for (int c = 0; c < 128; ++c) {
      short8 hv8 = *(const short8*)(hb + (size_t)c * 128);
      #pragma unroll
      for (int e = 0; e < 8; ++e) {
        float hv = bf2f((u16)hv8[e]);
        s0 += hv * fc_w[c * 8 + e];
        s1 += hv * fc_w[1024 + c * 8 + e];
      }
    }
    float mx = fmaxf(s0, s1);
    float e0 = __expf(s0 - mx), e1 = __expf(s1 - mx);
    float inv = 1.0f / (e0 + e1);
    out[b * 2]     = e0 * inv;
    out[b * 2 + 1] = e1 * inv;
  }
}

extern "C" void kernel_launch(void* const* d_in, const int* in_sizes, int n_in,
                              void* d_out, int out_size, void* d_ws, size_t ws_size,
                              hipStream_t stream) {
  const float* x    = (const float*)d_in[0];
  const float* wih0 = (const float*)d_in[1];
  const float* whh0 = (const float*)d_in[2];
  const float* bih0 = (const float*)d_in[3];
  const float* bhh0 = (const float*)d_in[4];
  const float* wih1 = (const float*)d_in[5];
  const float* whh1 = (const float*)d_in[6];
  const float* bih1 = (const float*)d_in[7];
  const float* bhh1 = (const float*)d_in[8];
  const float* fcw  = (const float*)d_in[9];
  const float* fcb  = (const float*)d_in[10];
  float* out = (float*)d_out;
  char* ws = (char*)d_ws;

  u16* xb    = (u16*)(ws + XB_OFF);
  u16* h0h   = (u16*)(ws + H0_OFF);
  u16* h1h   = (u16*)(ws + H1_OFF);
  u32* flags = (u32*)(ws + FL_OFF);

  (void)hipFuncSetAttribute((const void*)lstm_persist,
      hipFuncAttributeMaxDynamicSharedMemorySize, LDS_TOTAL);

  hipMemsetAsync(ws + FL_OFF, 0, FLAGS_LEN, stream);   // zero step flags
  prep_x<<<8192, 256, 0, stream>>>(x, xb);
  lstm_persist<<<256, 256, LDS_TOTAL, stream>>>(
      (const u16*)xb, wih0, whh0, bih0, bhh0, wih1, whh1, bih1, bhh1,
      h0h, h1h, flags, fcw, fcb, out);
}

// Round 16
// 3817.141 us; speedup vs baseline: 2.0202x; 1.3091x over previous
//
#include <hip/hip_runtime.h>

typedef __attribute__((ext_vector_type(8))) short short8;
typedef __attribute__((ext_vector_type(4))) float f32x4;
typedef __attribute__((ext_vector_type(2))) unsigned int u32x2;
typedef unsigned short u16;
typedef unsigned int u32;

// ---------------- workspace layout (bytes) ----------------
// xb:  [512 t][64 b][512 i] bf16                              = 33,554,432
// h0h: [513][4 g][128 chunk][16 b][8 u] bf16 (slot t+1=h[t])  = 67,239,936
// h1h: same                                                   = 67,239,936
// flags: [2 layer][4 group][128 chunk] monotonic, 32B stride  = 32,768
#define XB_OFF 0ul
#define H0_OFF 33554432ul
#define H1_OFF 100794368ul
#define FL_OFF 168034304ul
#define FLAGS_LEN 32768ul

#define LDS_TOTAL 131072   // weights only: 32 cols * K2 (K2=4096B for layer1)

__device__ __forceinline__ u16 f2bf(float f) {
  u32 u = __float_as_uint(f);
  return (u16)((u + 0x7fffu + ((u >> 16) & 1u)) >> 16);   // RNE
}
__device__ __forceinline__ float bf2f(u16 s) { return __uint_as_float(((u32)s) << 16); }

// x[b][t][i] fp32 -> xb[t][b][i] bf16
__global__ __launch_bounds__(256) void prep_x(const float* __restrict__ x,
                                              u16* __restrict__ xb) {
  u32 stride = gridDim.x * blockDim.x;
  for (u32 e = blockIdx.x * blockDim.x + threadIdx.x; e < 16777216u; e += stride) {
    u32 i = e & 511u, b = (e >> 9) & 63u, t = e >> 15;
    xb[e] = f2bf(x[((size_t)b << 18) + ((size_t)t << 9) + i]);
  }
}

// Persistent kernel, 256 blocks (1/CU), 256 threads (4 autonomous wave-chains).
// Blocks 0..127: layer0 (K=1536=[x|h0prev]); 128..255: layer1 (K=2048=[h0|h1prev]).
// Wave g = batch group (16 batches). mfma(A=W, B=h): C = [gate-col x batch] ->
// cell update is wave-local after one shfl_xor(32). NO barriers in the main loop;
// each wave runs poll -> load -> mfma -> nonlin -> store -> own-drain -> flag
// autonomously. Flags sc0sc1 (coherence point); h data loads plain-cached
// (fresh address per t: one L2 fill per XCD, then multicast).
__global__ __launch_bounds__(256, 1) void lstm_persist(
    const u16* __restrict__ xb,
    const float* __restrict__ wih0, const float* __restrict__ whh0,
    const float* __restrict__ bih0, const float* __restrict__ bhh0,
    const float* __restrict__ wih1, const float* __restrict__ whh1,
    const float* __restrict__ bih1, const float* __restrict__ bhh1,
    u16* __restrict__ h0h, u16* __restrict__ h1h,
    u32* __restrict__ flags,
    const float* __restrict__ fc_w, const float* __restrict__ fc_b,
    float* __restrict__ out) {
  extern __shared__ char smem[];
  const int cu = blockIdx.x;
  const int layer = cu >> 7;
  const int lcu = cu & 127;
  const int U0 = lcu * 8;
  const int K2 = layer ? 4096 : 3072;         // bytes per LDS weight column
  const int tid = threadIdx.x;

  // ---- startup: pack 32 weight cols (col-major k, byte ^ (n&7)<<4) ----
  for (int n = 0; n < 32; ++n) {
    const int grow = (n >> 3) * 1024 + U0 + (n & 7);
    char* colbase = smem + n * K2;
    const u32 swn = (u32)(n & 7) << 4;
    if (!layer) {
      const float* rih = wih0 + (size_t)grow * 512;
      const float* rhh = whh0 + (size_t)grow * 1024;
      for (int k = tid; k < 1536; k += 256) {
        float v = (k < 512) ? rih[k] : rhh[k - 512];
        *(u16*)(colbase + (((u32)k * 2u) ^ swn)) = f2bf(v);
      }
    } else {
      const float* rih = wih1 + (size_t)grow * 1024;
      const float* rhh = whh1 + (size_t)grow * 1024;
      for (int k = tid; k < 2048; k += 256) {
        float v = (k < 1024) ? rih[k] : rhh[k - 1024];
        *(u16*)(colbase + (((u32)k * 2u) ^ swn)) = f2bf(v);
      }
    }
  }
  __syncthreads();   // last barrier before the main loop

  const int g = tid >> 6;            // wave = batch group (16 batches)
  const int lane = tid & 63;
  const int lr = lane & 15;          // batch row within group / col within tile
  const int lq = lane >> 4;
  const u32 swz = (u32)(lr & 7) << 4;
  const char* wrow0 = smem + (size_t)lr * K2;         // cols 0-15 (i|f units)
  const char* wrow1 = smem + (size_t)(16 + lr) * K2;  // cols 16-31 (g|o units)

  // per-lane bias regs: unit u = 4*(lq&1) + r
  float bi[4], bf_[4], bg[4], bo[4];
  {
    const float* s1 = layer ? bih1 : bih0;
    const float* s2 = layer ? bhh1 : bhh0;
    const int ug = U0 + 4 * (lq & 1);
    #pragma unroll
    for (int r = 0; r < 4; ++r) {
      bi[r]  = s1[ug + r]        + s2[ug + r];
      bf_[r] = s1[1024 + ug + r] + s2[1024 + ug + r];
      bg[r]  = s1[2048 + ug + r] + s2[2048 + ug + r];
      bo[r]  = s1[3072 + ug + r] + s2[3072 + ug + r];
    }
  }
  float cs[4] = {0.f, 0.f, 0.f, 0.f};

  const u32* f0g = flags + (size_t)(0 * 4 + g) * 1024;   // 128 flags * 8 u32 stride
  const u32* f1g = flags + (size_t)(4 + g) * 1024;
  u32* myflag = flags + ((size_t)(layer * 4 + g) * 128 + (size_t)lcu) * 8;

  // wave-level poll: all 128 chunk flags of this (layer,group) >= target
  auto poll2 = [&](const u32* base, u32 target) {
    const u32* p1 = base + (u32)lane * 8u;
    const u32* p2 = base + (u32)(lane + 64) * 8u;
    for (;;) {
      u32 v1, v2;
      asm volatile("global_load_dword %0, %2, off sc0 sc1\n\t"
                   "global_load_dword %1, %3, off sc0 sc1\n\t"
                   "s_waitcnt vmcnt(0)"
                   : "=v"(v1), "=v"(v2) : "v"(p1), "v"(p2) : "memory");
      if (__all((int)((v1 >= target) & (v2 >= target)))) break;
      __builtin_amdgcn_s_sleep(1);
    }
  };

  f32x4 z4 = {0.f, 0.f, 0.f, 0.f};
  f32x4 acc0, acc1;    // tile0: cols 0-15 (i,f); tile1: cols 16-31 (g,o)

  auto mfma2 = [&](short8 hb8, int k0) {
    const u32 kb = ((u32)(k0 + lq * 8) * 2u) ^ swz;
    short8 a0 = *(const short8*)(wrow0 + kb);
    short8 a1 = *(const short8*)(wrow1 + kb);
    acc0 = __builtin_amdgcn_mfma_f32_16x16x32_bf16(a0, hb8, acc0, 0, 0, 0);
    acc1 = __builtin_amdgcn_mfma_f32_16x16x32_bf16(a1, hb8, acc1, 0, 0, 0);
  };

  // cell update (wave-local) + publish: 8B store -> own drain -> flag
  auto cell_publish = [&](int t, u16* hist) {
    float pf[4], po[4];
    #pragma unroll
    for (int r = 0; r < 4; ++r) {
      pf[r] = __shfl_xor(acc0[r], 32);   // partner's i|f  -> f for lq<2
      po[r] = __shfl_xor(acc1[r], 32);   // partner's g|o  -> o for lq<2
    }
    if (lq < 2) {
      u16 hb16[4];
      #pragma unroll
      for (int r = 0; r < 4; ++r) {
        float gi = acc0[r] + bi[r];
        float gf = pf[r]   + bf_[r];
        float gg = acc1[r] + bg[r];
        float go = po[r]   + bo[r];
        float ii = 1.0f / (1.0f + __expf(-gi));
        float ff = 1.0f / (1.0f + __expf(-gf));
        float gt = 1.0f - 2.0f / (__expf(2.0f * gg) + 1.0f);
        float oo = 1.0f / (1.0f + __expf(-go));
        cs[r] = ff * cs[r] + ii * gt;
        hb16[r] = f2bf(oo * (1.0f - 2.0f / (__expf(2.0f * cs[r]) + 1.0f)));
      }
      u32x2 pk;
      pk.x = (u32)hb16[0] | ((u32)hb16[1] << 16);
      pk.y = (u32)hb16[2] | ((u32)hb16[3] << 16);
      // h[t+1][g][lcu][b=lr][u=4*lq..+4]
      u16* dst = hist + (size_t)(t + 1) * 65536 + (size_t)g * 16384
                 + (size_t)lcu * 128 + (size_t)lr * 8 + 4 * lq;
      asm volatile("global_store_dwordx2 %0, %1, off sc0 sc1" :: "v"(dst), "v"(pk));
    }
    asm volatile("s_waitcnt vmcnt(0)" ::: "memory");   // own stores ack'd at IC
    if (lane == 0)
      asm volatile("global_store_dword %0, %1, off sc0 sc1"
                   :: "v"(myflag), "v"((u32)(t + 1)));
  };

  if (!layer) {
    // ================= layer 0: K = [x(512) | h0prev(1024)] =================
    for (int t = 0; t < 512; ++t) {
      acc0 = z4; acc1 = z4;
      // x part first (no dependency): plain cached loads
      const u16* xp = xb + (size_t)t * 32768 + (size_t)(g * 16 + lr) * 512 + lq * 8;
      short8 X[16];
      #pragma unroll
      for (int j = 0; j < 16; ++j) X[j] = *(const short8*)(xp + j * 32);
      #pragma unroll
      for (int j = 0; j < 16; ++j) mfma2(X[j], j * 32);
      if (t > 0) {
        poll2(f0g, (u32)t);
        const u16* hp = h0h + (size_t)t * 65536 + (size_t)g * 16384 + (size_t)lr * 8;
        short8 H[32];
        #pragma unroll
        for (int j = 0; j < 32; ++j)
          H[j] = *(const short8*)(hp + (size_t)(j * 4 + lq) * 128);
        #pragma unroll
        for (int j = 0; j < 32; ++j) mfma2(H[j], 512 + j * 32);
      }
      cell_publish(t, h0h);
    }
  } else {
    // ============== layer 1: K = [h0cur(1024) | h1prev(1024)] ==============
    for (int t = 0; t < 512; ++t) {
      acc0 = z4; acc1 = z4;
      if (t > 0) {
        poll2(f1g, (u32)t);     // own-layer recurrence
        const u16* hp1 = h1h + (size_t)t * 65536 + (size_t)g * 16384 + (size_t)lr * 8;
        short8 H1[32];
        #pragma unroll
        for (int j = 0; j < 32; ++j)
          H1[j] = *(const short8*)(hp1 + (size_t)(j * 4 + lq) * 128);
        #pragma unroll
        for (int j = 0; j < 32; ++j) mfma2(H1[j], 1024 + j * 32);
      }
      poll2(f0g, (u32)(t + 1));  // fresh dependency: h0[t]
      const u16* hp0 = h0h + (size_t)(t + 1) * 65536 + (size_t)g * 16384 + (size_t)lr * 8;
      short8 H0[32];
      #pragma unroll
      for (int j = 0; j < 32; ++j)
        H0[j] = *(const short8*)(hp0 + (size_t)(j * 4 + lq) * 128);
      #pragma unroll
      for (int j = 0; j < 32; ++j) mfma2(H0[j], j * 32);
      cell_publish(t, h1h);
    }
  }

  // ---- FC + softmax epilogue: block 0, wave 0 (reads h1[511] = slot 512) ----
  if (cu == 0 && g == 0) {
    #pragma unroll
    for (int j = 0; j < 8; ++j) {   // all 512 layer-1 flags >= 512
      const u32* p = flags + (size_t)(512 + j * 64 + lane) * 8;
      for (;;) {
        u32 v;
        asm volatile("global_load_dword %0, %1, off sc0 sc1\n\ts_waitcnt vmcnt(0)"
                     : "=v"(v) : "v"(p) : "memory");
        if (v >= 512u) break;
        __builtin_amdgcn_s_sleep(1);
      }
    }
    const int b = lane;                       // one batch per lane
    const u16* hb = h1h + (size_t)512 * 65536 + (size_t)(b >> 4) * 16384
                    + (size_t)(b & 15) * 8;
    float s0 = fc_b[0], s1 = fc_b[1];
    for (int c = 0; c < 128; ++c) {
      short8 hv8 = *(const short8*)(hb + (size_t)c * 128);
      #pragma unroll
      for (int e = 0; e < 8; ++e) {
        float hv = bf2f((u16)hv8[e]);
        s0 += hv * fc_w[c * 8 + e];
        s1 += hv * fc_w[1024 + c * 8 + e];
      }
    }
    float mx = fmaxf(s0, s1);
    float e0 = __expf(s0 - mx), e1 = __expf(s1 - mx);
    float inv = 1.0f / (e0 + e1);
    out[b * 2]     = e0 * inv;
    out[b * 2 + 1] = e1 * inv;
  }
}

extern "C" void kernel_launch(void* const* d_in, const int* in_sizes, int n_in,
                              void* d_out, int out_size, void* d_ws, size_t ws_size,
                              hipStream_t stream) {
  const float* x    = (const float*)d_in[0];
  const float* wih0 = (const float*)d_in[1];
  const float* whh0 = (const float*)d_in[2];
  const float* bih0 = (const float*)d_in[3];
  const float* bhh0 = (const float*)d_in[4];
  const float* wih1 = (const float*)d_in[5];
  const float* whh1 = (const float*)d_in[6];
  const float* bih1 = (const float*)d_in[7];
  const float* bhh1 = (const float*)d_in[8];
  const float* fcw  = (const float*)d_in[9];
  const float* fcb  = (const float*)d_in[10];
  float* out = (float*)d_out;
  char* ws = (char*)d_ws;

  u16* xb    = (u16*)(ws + XB_OFF);
  u16* h0h   = (u16*)(ws + H0_OFF);
  u16* h1h   = (u16*)(ws + H1_OFF);
  u32* flags = (u32*)(ws + FL_OFF);

  (void)hipFuncSetAttribute((const void*)lstm_persist,
      hipFuncAttributeMaxDynamicSharedMemorySize, LDS_TOTAL);

  hipMemsetAsync(ws + FL_OFF, 0, FLAGS_LEN, stream);   // zero step flags
  prep_x<<<8192, 256, 0, stream>>>(x, xb);
  lstm_persist<<<256, 256, LDS_TOTAL, stream>>>(
      (const u16*)xb, wih0, whh0, bih0, bhh0, wih1, whh1, bih1, bhh1,
      h0h, h1h, flags, fcw, fcb, out);
}